// Round 17
// baseline (212.855 us; speedup 1.0000x reference)
//
#include <hip/hip_runtime.h>

#define NN 50000
#define NE 800000
#define DD 128
#define ED 32
#define NB 196          // ceil(NN/256)
#define NZB 1563        // agg-zero blocks: 1563*256*16 >= NN*DD floats

typedef short  bf16x8 __attribute__((ext_vector_type(8)));
typedef float  f32x4  __attribute__((ext_vector_type(4)));
typedef float  f32x16 __attribute__((ext_vector_type(16)));

__device__ __forceinline__ float4 ld4(const float* p) {
    return *reinterpret_cast<const float4*>(p);
}
__device__ __forceinline__ short f2bf(float f) {   // RTN-even f32 -> bf16 bits
    unsigned u = __float_as_uint(f);
    u += 0x7fffu + ((u >> 16) & 1u);
    return (short)(u >> 16);
}
__device__ __forceinline__ int sniff64(const int* ei) {
    // int64 indices < 2^32: every odd 32-bit word is zero.
    return ((ei[1] | ei[3] | ei[5] | ei[7]) == 0) ? 1 : 0;
}

// ============================================================ fused setup
// blocks [0,6250): xb[n][c*4+bb] = bf16(x[n][bb*32+c])  (permuted x cast)
// blocks [6250,8298): dst histogram
// block 8298: We -> per-lane MFMA B-fragment table (64 lanes x 128B)
__global__ __launch_bounds__(256)
void k_setup(const float* __restrict__ x, const int* __restrict__ ei,
             const float* __restrict__ We, unsigned int* __restrict__ xb,
             int* __restrict__ counts, unsigned short* __restrict__ Bft)
{
    const int tid = threadIdx.x;
    if (blockIdx.x < 6250) {
        const int t = blockIdx.x * 256 + tid;
        if (t >= NN * 32) return;
        const int n = t >> 5, c = t & 31;
        const float* xr = x + (size_t)n * DD + c;
        const unsigned b0 = (unsigned short)f2bf(xr[0]);
        const unsigned b1 = (unsigned short)f2bf(xr[32]);
        const unsigned b2 = (unsigned short)f2bf(xr[64]);
        const unsigned b3 = (unsigned short)f2bf(xr[96]);
        xb[(size_t)n * 64 + c * 2]     = b0 | (b1 << 16);
        xb[(size_t)n * 64 + c * 2 + 1] = b2 | (b3 << 16);
    } else if (blockIdx.x < 8298) {
        const int is64 = sniff64(ei);
        const int2* ei2 = (const int2*)ei;
        for (int e = (blockIdx.x - 6250) * 256 + tid; e < NE; e += 2048 * 256) {
            const int dst = is64 ? ei2[NE + e].x : ei[NE + e];
            atomicAdd(&counts[dst], 1);
        }
    } else if (tid < 64) {
        const int col = tid & 31, h = tid >> 5;
#pragma unroll
        for (int bb = 0; bb < 4; ++bb)
#pragma unroll
            for (int s = 0; s < 2; ++s)
#pragma unroll
                for (int i = 0; i < 8; ++i)
                    Bft[tid * 64 + (bb * 2 + s) * 8 + i] =
                        (unsigned short)f2bf(We[(s * 16 + h * 8 + i) * DD + bb * 32 + col]);
    }
}

// ============================================================ fused scan
// Replaces bsum+scanb+rowptr (3 dispatches) with ONE kernel:
//  blocks [0,NB): 3-stage scan with device-scope atomic spin-sync.
//    NB=196 <= 256 CUs -> all scan blocks co-resident; cross-block data
//    (bsum/bexcl/syncf) moves exclusively via device-scope atomics, so
//    per-XCD L2 non-coherence cannot serve stale values.
//  blocks [NB, NB+NZB): zero the agg buffer (exit immediately; they never
//    join the sync, and their retirement frees CUs -> no deadlock).
__global__ __launch_bounds__(256)
void k_scan3(const int* __restrict__ counts, int* __restrict__ cursor,
             int* __restrict__ bsum, int* __restrict__ bexcl,
             int* __restrict__ syncf, float* __restrict__ aggz)
{
    const int tid = threadIdx.x, lane = tid & 63, w = tid >> 6;
    const int bid = blockIdx.x;

    if (bid >= NB) {                      // ---- agg zeroing blocks
        const int base = ((bid - NB) * 256 + tid) * 16;
        if (base < NN * DD) {
            const float4 z = { 0.f, 0.f, 0.f, 0.f };
            float4* p = reinterpret_cast<float4*>(aggz + base);
            p[0] = z; p[1] = z; p[2] = z; p[3] = z;
        }
        return;
    }

    __shared__ int wsum[4], wexcl1[4], wsum2[4], wexcl2[4];

    // ---- stage 1: per-block sum of counts
    const int i = bid * 256 + tid;
    const int c = (i < NN) ? counts[i] : 0;
    int s = c;
#pragma unroll
    for (int off = 1; off < 64; off <<= 1) {
        const int t = __shfl_up(s, off, 64);
        if (lane >= off) s += t;
    }
    if (lane == 63) wsum[w] = s;
    __syncthreads();
    if (tid == 0) {
        atomicExch(&bsum[bid], wsum[0] + wsum[1] + wsum[2] + wsum[3]);
        __threadfence();
        atomicAdd(&syncf[0], 1);
        int r = 0;
#pragma unroll
        for (int k = 0; k < 4; ++k) { wexcl1[k] = r; r += wsum[k]; }
    }

    // ---- stage 2: block 0 scans bsum -> bexcl
    if (bid == 0) {
        if (tid == 0) { while (atomicAdd(&syncf[0], 0) < NB) { } }
        __syncthreads();
        const int v = (tid < NB) ? atomicAdd(&bsum[tid], 0) : 0;
        int s2 = v;
#pragma unroll
        for (int off = 1; off < 64; off <<= 1) {
            const int t = __shfl_up(s2, off, 64);
            if (lane >= off) s2 += t;
        }
        if (lane == 63) wsum2[w] = s2;
        __syncthreads();
        if (tid == 0) {
            int r = 0;
#pragma unroll
            for (int k = 0; k < 4; ++k) { wexcl2[k] = r; r += wsum2[k]; }
        }
        __syncthreads();
        if (tid < NB) atomicExch(&bexcl[tid], wexcl2[w] + s2 - v);
        __threadfence();
        if (tid == 0) atomicExch(&syncf[1], 1);
    }

    // ---- stage 3: all scan blocks finish cursor
    if (tid == 0) { while (atomicAdd(&syncf[1], 0) == 0) { } }
    __syncthreads();
    const int be_ = atomicAdd(&bexcl[bid], 0);
    if (i < NN) cursor[i] = be_ + wexcl1[w] + s - c;
}

// ============================================================ scatter + row copy
// Block handles 128 edges. The 8 ea float2 loads are issued BEFORE the
// atomic/sync phase (independent) so HBM read latency hides under the
// cursor atomics. Phase 1: 128 threads compute sorted pos, write
// sdat4[pos] = src|dst<<16, park pos in LDS. Phase 2: convert + store the
// sorted bf16 rows ebs[pos] (regular stores — NT / f32-row variants both
// measured worse; bf16 keeps the working set L3-resident).
__global__ __launch_bounds__(256)
void k_scatter2(const int* __restrict__ ei, int* __restrict__ cursor,
                const float* __restrict__ ea, int* __restrict__ sdat4,
                unsigned int* __restrict__ ebs)
{
    const int tid = threadIdx.x;
    const int e0  = blockIdx.x * 128;

    // prefetch ea rows (coalesced; independent of the atomics below)
    float2 v[8];
#pragma unroll
    for (int it = 0; it < 8; ++it) {
        const int task = it * 256 + tid;
        const int el   = task >> 4;       // 0..127
        const int part = task & 15;
        v[it] = *reinterpret_cast<const float2*>(
                    ea + (size_t)(e0 + el) * ED + part * 2);
    }

    __shared__ int spos[128];
    if (tid < 128) {
        const int is64 = sniff64(ei);
        const int2* ei2 = (const int2*)ei;
        const int e   = e0 + tid;
        const int src = is64 ? ei2[e].x : ei[e];
        const int dst = is64 ? ei2[NE + e].x : ei[NE + e];
        const int pos = atomicAdd(&cursor[dst], 1);
        sdat4[pos] = src | (dst << 16);
        spos[tid] = pos;
    }
    __syncthreads();
#pragma unroll
    for (int it = 0; it < 8; ++it) {
        const int task = it * 256 + tid;
        const int el   = task >> 4;
        const int part = task & 15;
        const unsigned lo = (unsigned short)f2bf(v[it].x);
        const unsigned hi = (unsigned short)f2bf(v[it].y);
        ebs[(size_t)spos[el] * 16 + part] = lo | (hi << 16);
    }
}

// ============================================================ aggregation
// One wave per TWO consecutive 32-edge dst-sorted chunks (atomic L2
// locality). B-fragments pre-converted from Bft (8x16B loads). A = sorted
// bf16 ea rows read SEQUENTIALLY from ebs. C-init = one uint2 (4 bf16 dims
// bb*32+col) per reg from the permuted xb gather; chunk1's gathers are
// issued before chunk0's epilogue so their latency hides under VALU.
__device__ __forceinline__ void agg_epilogue(f32x16 (&C)[4], const float beb[4],
                                             int dstv, int lane, int col, int h,
                                             float* __restrict__ agg)
{
#pragma unroll
    for (int bb = 0; bb < 4; ++bb)
#pragma unroll
        for (int reg = 0; reg < 16; ++reg)
            C[bb][reg] = fmaxf(C[bb][reg] + beb[bb], 0.0f);

    const int  prv  = __shfl(dstv, (lane == 0) ? 0 : lane - 1, 64);
    const bool flag = (lane < 32) && ((col == 0) || (dstv != prv));
    unsigned rem = (unsigned)(__ballot(flag) & 0xFFFFFFFFull);

    while (rem) {
        const int ms = __ffs((int)rem) - 1;
        rem &= rem - 1;
        const int hi = rem ? (__ffs((int)rem) - 1) : 32;
        const int d  = __shfl(dstv, ms, 64);

        float v0 = 0.f, v1 = 0.f, v2 = 0.f, v3 = 0.f;
#pragma unroll
        for (int reg = 0; reg < 16; ++reg) {
            const int E = (reg & 3) + 8 * (reg >> 2) + 4 * h;
            const float mk = (E >= ms && E < hi) ? 1.0f : 0.0f;
            v0 = fmaf(mk, C[0][reg], v0);
            v1 = fmaf(mk, C[1][reg], v1);
            v2 = fmaf(mk, C[2][reg], v2);
            v3 = fmaf(mk, C[3][reg], v3);
        }
        v0 += __shfl_xor(v0, 32, 64);
        v1 += __shfl_xor(v1, 32, 64);
        v2 += __shfl_xor(v2, 32, 64);
        v3 += __shfl_xor(v3, 32, 64);

        float* ar = agg + (size_t)d * DD + h * 64 + col;
        unsafeAtomicAdd(ar,      h ? v2 : v0);
        unsafeAtomicAdd(ar + 32, h ? v3 : v1);
    }
}

__global__ __launch_bounds__(256, 2)
void k_aggE(const unsigned int* __restrict__ xb, const unsigned int* __restrict__ ebs,
            const unsigned short* __restrict__ Bft, const float* __restrict__ be,
            const int* __restrict__ sdat4, float* __restrict__ agg)
{
    const int lane = threadIdx.x & 63;
    const int col  = lane & 31;
    const int h    = lane >> 5;
    const int wid  = (blockIdx.x << 2) | (threadIdx.x >> 6);   // 0..12499
    const int c0   = wid * 2, c1 = wid * 2 + 1;

    // B fragments: pre-converted, 8 x 16B per lane (L2-resident 8KB table)
    bf16x8 Bf[4][2];
    {
        const bf16x8* bp_ = reinterpret_cast<const bf16x8*>(Bft + lane * 64);
#pragma unroll
        for (int bb = 0; bb < 4; ++bb) {
            Bf[bb][0] = bp_[bb * 2];
            Bf[bb][1] = bp_[bb * 2 + 1];
        }
    }
    float beb[4];
#pragma unroll
    for (int bb = 0; bb < 4; ++bb) beb[bb] = be[bb * 32 + col];

    // descriptors for both chunks
    const int sd0 = sdat4[c0 * 32 + col];
    const int sd1 = sdat4[c1 * 32 + col];

    // A fragments: lane's edge rows, pre-converted bf16, sequential stream
    const unsigned int* ebr0 = ebs + ((size_t)c0 * 32 + col) * 16;
    const unsigned int* ebr1 = ebs + ((size_t)c1 * 32 + col) * 16;
    const bf16x8 A00 = *reinterpret_cast<const bf16x8*>(ebr0 + h * 4);
    const bf16x8 A01 = *reinterpret_cast<const bf16x8*>(ebr0 + 8 + h * 4);
    const bf16x8 A10 = *reinterpret_cast<const bf16x8*>(ebr1 + h * 4);
    const bf16x8 A11 = *reinterpret_cast<const bf16x8*>(ebr1 + 8 + h * 4);

    // chunk0 gathers
    uint2 w0[16];
#pragma unroll
    for (int reg = 0; reg < 16; ++reg) {
        const int E   = (reg & 3) + 8 * (reg >> 2) + 4 * h;
        const int src = __shfl(sd0, E, 64) & 0xFFFF;
        w0[reg] = *reinterpret_cast<const uint2*>(xb + (size_t)src * 64 + col * 2);
    }

    f32x16 C[4];
#pragma unroll
    for (int reg = 0; reg < 16; ++reg) {
        C[0][reg] = __uint_as_float(w0[reg].x << 16);
        C[1][reg] = __uint_as_float(w0[reg].x & 0xFFFF0000u);
        C[2][reg] = __uint_as_float(w0[reg].y << 16);
        C[3][reg] = __uint_as_float(w0[reg].y & 0xFFFF0000u);
    }
#pragma unroll
    for (int bb = 0; bb < 4; ++bb) {
        C[bb] = __builtin_amdgcn_mfma_f32_32x32x16_bf16(A00, Bf[bb][0], C[bb], 0, 0, 0);
        C[bb] = __builtin_amdgcn_mfma_f32_32x32x16_bf16(A01, Bf[bb][1], C[bb], 0, 0, 0);
    }

    // issue chunk1 gathers BEFORE chunk0 epilogue (latency hides under VALU)
    uint2 w1[16];
#pragma unroll
    for (int reg = 0; reg < 16; ++reg) {
        const int E   = (reg & 3) + 8 * (reg >> 2) + 4 * h;
        const int src = __shfl(sd1, E, 64) & 0xFFFF;
        w1[reg] = *reinterpret_cast<const uint2*>(xb + (size_t)src * 64 + col * 2);
    }

    agg_epilogue(C, beb, ((unsigned)sd0) >> 16, lane, col, h, agg);

    // chunk1
#pragma unroll
    for (int reg = 0; reg < 16; ++reg) {
        C[0][reg] = __uint_as_float(w1[reg].x << 16);
        C[1][reg] = __uint_as_float(w1[reg].x & 0xFFFF0000u);
        C[2][reg] = __uint_as_float(w1[reg].y << 16);
        C[3][reg] = __uint_as_float(w1[reg].y & 0xFFFF0000u);
    }
#pragma unroll
    for (int bb = 0; bb < 4; ++bb) {
        C[bb] = __builtin_amdgcn_mfma_f32_32x32x16_bf16(A10, Bf[bb][0], C[bb], 0, 0, 0);
        C[bb] = __builtin_amdgcn_mfma_f32_32x32x16_bf16(A11, Bf[bb][1], C[bb], 0, 0, 0);
    }
    agg_epilogue(C, beb, ((unsigned)sd1) >> 16, lane, col, h, agg);
}

// ============================================================ fused conv+gate
// Phase 1: conv = (x+agg)@Wc+bc, plain bf16 (Wc in sBh). Then sBh is
// re-staged with Wg and each wave parks its conv tile (f32) in its quarter
// of sBl as the gate-GEMM A-operand. Phase 2: z = conv@Wg(+imp row)+bg;
// epilogue: sigmoid, blend, out write, prop = out@Wp+bp. agg aliases out.
__global__ __launch_bounds__(256)
void k_cg(const float* __restrict__ x, const float* agg,
          const float* __restrict__ Wc, const float* __restrict__ bc,
          const float* __restrict__ imp, const float* __restrict__ Wg,
          const float* __restrict__ bg, const float* __restrict__ Wp,
          const float* __restrict__ bp, float* outp, float* __restrict__ prop)
{
    __shared__ short sBh[2048 * 8];   // 32KB: Wc, then Wg
    __shared__ short sBl[2048 * 8];   // 32KB: conv-tile scratch (phase 2)
    for (int idx = threadIdx.x; idx < 2048; idx += 256) {
        const int kk = idx >> 9;
        const int b  = (idx >> 6) & 7;
        const int l  = idx & 63;
        const int row0 = kk * 32 + ((l >> 4) << 3);
        const int col  = b * 16 + (l & 15);
        bf16x8 h8;
#pragma unroll
        for (int j = 0; j < 8; ++j)
            h8[j] = f2bf(Wc[(row0 + j) * DD + col]);
        *reinterpret_cast<bf16x8*>(&sBh[idx * 8]) = h8;
    }
    __syncthreads();

    const int lane = threadIdx.x & 63;
    const int ncol = lane & 15;
    const int krow = (lane >> 4) << 3;
    const int grp  = lane >> 4;
    const int wib  = threadIdx.x >> 6;
    const int wid  = (blockIdx.x << 2) | wib;
    const bool live = (wid < NN / 16);
    const int m0 = live ? wid * 16 : 0;

    // ---- phase 1: conv GEMM (plain bf16)
    f32x4 C[8];
#pragma unroll
    for (int b = 0; b < 8; ++b) {
        const float bcv = bc[b * 16 + ncol];
        f32x4 c = { bcv, bcv, bcv, bcv };
        C[b] = c;
    }
    {
        const float* xrow = x   + (size_t)(m0 + ncol) * DD + krow;
        const float* grow = agg + (size_t)(m0 + ncol) * DD + krow;
#pragma unroll
        for (int kk = 0; kk < 4; ++kk) {
            const float4 x0 = ld4(xrow + kk * 32), x1 = ld4(xrow + kk * 32 + 4);
            const float4 g0 = ld4(grow + kk * 32), g1 = ld4(grow + kk * 32 + 4);
            const float av[8] = { x0.x + g0.x, x0.y + g0.y, x0.z + g0.z, x0.w + g0.w,
                                  x1.x + g1.x, x1.y + g1.y, x1.z + g1.z, x1.w + g1.w };
            bf16x8 Ah;
#pragma unroll
            for (int j = 0; j < 8; ++j) Ah[j] = f2bf(av[j]);
#pragma unroll
            for (int b = 0; b < 8; ++b) {
                const bf16x8 Bh = *reinterpret_cast<const bf16x8*>(&sBh[((kk * 8 + b) * 64 + lane) * 8]);
                C[b] = __builtin_amdgcn_mfma_f32_16x16x32_bf16(Ah, Bh, C[b], 0, 0, 0);
            }
        }
    }
    __syncthreads();   // everyone done reading Wc

    // ---- restage: Wg -> sBh (cooperative); conv tile -> sBl (per wave)
    for (int idx = threadIdx.x; idx < 2048; idx += 256) {
        const int kk = idx >> 9;
        const int b  = (idx >> 6) & 7;
        const int l  = idx & 63;
        const int row0 = kk * 32 + ((l >> 4) << 3);
        const int col  = b * 16 + (l & 15);
        bf16x8 h8;
#pragma unroll
        for (int j = 0; j < 8; ++j)
            h8[j] = f2bf(Wg[(row0 + j) * DD + col]);
        *reinterpret_cast<bf16x8*>(&sBh[idx * 8]) = h8;
    }
    float* scr = reinterpret_cast<float*>(sBl) + wib * 2048;   // 16x128 f32
#pragma unroll
    for (int r = 0; r < 4; ++r)
#pragma unroll
        for (int b = 0; b < 8; ++b)
            scr[(grp * 4 + r) * DD + b * 16 + ncol] = C[b][r];
    __syncthreads();

    // ---- phase 2: z GEMM (plain bf16)
    f32x4 Z[8];
#pragma unroll
    for (int b = 0; b < 8; ++b) {
        const float bgv = bg[b * 16 + ncol];
        f32x4 z = { bgv, bgv, bgv, bgv };
        Z[b] = z;
    }
#pragma unroll
    for (int kk = 0; kk < 4; ++kk) {
        const float4 a0 = ld4(scr + ncol * DD + kk * 32 + krow);
        const float4 a1 = ld4(scr + ncol * DD + kk * 32 + krow + 4);
        const float av[8] = { a0.x, a0.y, a0.z, a0.w, a1.x, a1.y, a1.z, a1.w };
        bf16x8 Ah;
#pragma unroll
        for (int j = 0; j < 8; ++j) Ah[j] = f2bf(av[j]);
#pragma unroll
        for (int b = 0; b < 8; ++b) {
            const bf16x8 Bh = *reinterpret_cast<const bf16x8*>(&sBh[((kk * 8 + b) * 64 + lane) * 8]);
            Z[b] = __builtin_amdgcn_mfma_f32_16x16x32_bf16(Ah, Bh, Z[b], 0, 0, 0);
        }
    }

    if (!live) return;

    // ---- epilogue
    float wgi[8], wp8[8];
#pragma unroll
    for (int b = 0; b < 8; ++b) {
        wgi[b] = Wg[DD * DD + b * 16 + ncol];   // importance row (row 128)
        wp8[b] = Wp[b * 16 + ncol];
    }
    const float bps = bp[0];

    float s[4] = { 0.f, 0.f, 0.f, 0.f };
#pragma unroll
    for (int r = 0; r < 4; ++r) {
        const int m = m0 + grp * 4 + r;
        const float im = imp[m];
        const float* xr = x + (size_t)m * DD + ncol;
        float* orow = outp + (size_t)m * DD + ncol;
#pragma unroll
        for (int b = 0; b < 8; ++b) {
            const float a = Z[b][r] + im * wgi[b];
            const float g = 1.0f / (1.0f + expf(-a));
            const float xv = xr[b * 16];
            const float o = fmaf(g, C[b][r] - xv, xv);
            orow[b * 16] = o;
            s[r] += o * wp8[b];
        }
    }
#pragma unroll
    for (int off = 1; off < 16; off <<= 1) {
        s[0] += __shfl_xor(s[0], off, 64);
        s[1] += __shfl_xor(s[1], off, 64);
        s[2] += __shfl_xor(s[2], off, 64);
        s[3] += __shfl_xor(s[3], off, 64);
    }
    if (ncol < 4) {
        const float v = (ncol == 0) ? s[0] : (ncol == 1) ? s[1] : (ncol == 2) ? s[2] : s[3];
        prop[m0 + grp * 4 + ncol] = v + bps;
    }
}

extern "C" void kernel_launch(void* const* d_in, const int* in_sizes, int n_in,
                              void* d_out, int out_size, void* d_ws, size_t ws_size,
                              hipStream_t stream) {
    const float* x   = (const float*)d_in[0];
    const int*   ei  = (const int*)d_in[1];
    const float* ea  = (const float*)d_in[2];
    const float* imp = (const float*)d_in[3];
    const float* We  = (const float*)d_in[4];
    const float* be  = (const float*)d_in[5];
    const float* Wc  = (const float*)d_in[6];
    const float* bc  = (const float*)d_in[7];
    const float* Wg  = (const float*)d_in[8];
    const float* bg  = (const float*)d_in[9];
    const float* Wp  = (const float*)d_in[10];
    const float* bp  = (const float*)d_in[11];

    float* out  = (float*)d_out;                 // [NN, DD]; doubles as agg
    float* prop = out + (size_t)NN * DD;         // [NN]
    float* agg  = out;                           // aliased (see k_cg note)

    // ws layout (~68.6 MB; proven available)
    int*            counts = (int*)d_ws;                               // NN
    int*            syncf  = (int*)((char*)d_ws + 200000);             // 2 (zeroed with counts)
    int*            cursor = (int*)((char*)d_ws + 204800);             // NN
    int*            bsum   = (int*)((char*)d_ws + 409600);             // NB
    int*            bexcl  = (int*)((char*)d_ws + 413696);             // NB
    unsigned short* Bft    = (unsigned short*)((char*)d_ws + 417792);  // 64*64 u16
    int*            sdat4  = (int*)((char*)d_ws + 1048576);            // NE int
    unsigned int*   xb     = (unsigned int*)((char*)d_ws + 4456448);   // NN*DD bf16 (permuted)
    unsigned int*   ebs    = (unsigned int*)((char*)d_ws + 17301504);  // NE*ED bf16 (sorted)

    hipMemsetAsync(d_ws, 0, 200064, stream);     // counts + syncf
    hipLaunchKernelGGL(k_setup,    dim3(8299),     dim3(256), 0, stream,
                       x, ei, We, xb, counts, Bft);
    hipLaunchKernelGGL(k_scan3,    dim3(NB + NZB), dim3(256), 0, stream,
                       counts, cursor, bsum, bexcl, syncf, agg);
    hipLaunchKernelGGL(k_scatter2, dim3(6250),     dim3(256), 0, stream,
                       ei, cursor, ea, sdat4, ebs);
    hipLaunchKernelGGL(k_aggE,     dim3(3125),     dim3(256), 0, stream,
                       xb, ebs, Bft, be, sdat4, agg);
    hipLaunchKernelGGL(k_cg,       dim3(782),      dim3(256), 0, stream,
                       x, agg, Wc, bc, imp, Wg, bg, Wp, bp, out, prop);
}

// Round 18
// 201.526 us; speedup vs baseline: 1.0562x; 1.0562x over previous
//
#include <hip/hip_runtime.h>

#define NN 50000
#define NE 800000
#define DD 128
#define ED 32
#define NB 196          // ceil(NN/256)

typedef short  bf16x8 __attribute__((ext_vector_type(8)));
typedef float  f32x4  __attribute__((ext_vector_type(4)));
typedef float  f32x16 __attribute__((ext_vector_type(16)));

__device__ __forceinline__ float4 ld4(const float* p) {
    return *reinterpret_cast<const float4*>(p);
}
__device__ __forceinline__ short f2bf(float f) {   // RTN-even f32 -> bf16 bits
    unsigned u = __float_as_uint(f);
    u += 0x7fffu + ((u >> 16) & 1u);
    return (short)(u >> 16);
}
__device__ __forceinline__ int sniff64(const int* ei) {
    // int64 indices < 2^32: every odd 32-bit word is zero.
    return ((ei[1] | ei[3] | ei[5] | ei[7]) == 0) ? 1 : 0;
}

// ============================================================ fused setup
// blocks [0,6250): xb[n][c*4+bb] = bf16(x[n][bb*32+c])  (permuted x cast)
// blocks [6250,8298): dst histogram
// block 8298: We -> per-lane MFMA B-fragment table (64 lanes x 128B)
__global__ __launch_bounds__(256)
void k_setup(const float* __restrict__ x, const int* __restrict__ ei,
             const float* __restrict__ We, unsigned int* __restrict__ xb,
             int* __restrict__ counts, unsigned short* __restrict__ Bft)
{
    const int tid = threadIdx.x;
    if (blockIdx.x < 6250) {
        const int t = blockIdx.x * 256 + tid;
        if (t >= NN * 32) return;
        const int n = t >> 5, c = t & 31;
        const float* xr = x + (size_t)n * DD + c;
        const unsigned b0 = (unsigned short)f2bf(xr[0]);
        const unsigned b1 = (unsigned short)f2bf(xr[32]);
        const unsigned b2 = (unsigned short)f2bf(xr[64]);
        const unsigned b3 = (unsigned short)f2bf(xr[96]);
        xb[(size_t)n * 64 + c * 2]     = b0 | (b1 << 16);
        xb[(size_t)n * 64 + c * 2 + 1] = b2 | (b3 << 16);
    } else if (blockIdx.x < 8298) {
        const int is64 = sniff64(ei);
        const int2* ei2 = (const int2*)ei;
        for (int e = (blockIdx.x - 6250) * 256 + tid; e < NE; e += 2048 * 256) {
            const int dst = is64 ? ei2[NE + e].x : ei[NE + e];
            atomicAdd(&counts[dst], 1);
        }
    } else if (tid < 64) {
        const int col = tid & 31, h = tid >> 5;
#pragma unroll
        for (int bb = 0; bb < 4; ++bb)
#pragma unroll
            for (int s = 0; s < 2; ++s)
#pragma unroll
                for (int i = 0; i < 8; ++i)
                    Bft[tid * 64 + (bb * 2 + s) * 8 + i] =
                        (unsigned short)f2bf(We[(s * 16 + h * 8 + i) * DD + bb * 32 + col]);
    }
}

// ============================================================ CSR scan chain
__global__ __launch_bounds__(256)
void k_bsum(const int* __restrict__ counts, int* __restrict__ bsum) {
    const int i = blockIdx.x * 256 + threadIdx.x;
    int c = (i < NN) ? counts[i] : 0;
#pragma unroll
    for (int off = 32; off; off >>= 1) c += __shfl_xor(c, off, 64);
    __shared__ int ws4[4];
    if ((threadIdx.x & 63) == 0) ws4[threadIdx.x >> 6] = c;
    __syncthreads();
    if (threadIdx.x == 0) bsum[blockIdx.x] = ws4[0] + ws4[1] + ws4[2] + ws4[3];
}

__global__ __launch_bounds__(256)
void k_scanb(const int* __restrict__ bsum, int* __restrict__ bexcl) {
    const int tid = threadIdx.x, lane = tid & 63, w = tid >> 6;
    const int v = (tid < NB) ? bsum[tid] : 0;
    int s = v;
#pragma unroll
    for (int off = 1; off < 64; off <<= 1) {
        const int t = __shfl_up(s, off, 64);
        if (lane >= off) s += t;
    }
    __shared__ int wsum[4], wexcl[4];
    if (lane == 63) wsum[w] = s;
    __syncthreads();
    if (tid == 0) {
        int r = 0;
#pragma unroll
        for (int k = 0; k < 4; ++k) { wexcl[k] = r; r += wsum[k]; }
    }
    __syncthreads();
    if (tid < NB) bexcl[tid] = wexcl[w] + s - v;
}

__global__ __launch_bounds__(256)
void k_rowptr(const int* __restrict__ counts, const int* __restrict__ bexcl,
              int* __restrict__ cursor) {
    const int tid = threadIdx.x, lane = tid & 63, w = tid >> 6;
    const int i = blockIdx.x * 256 + tid;
    const int c = (i < NN) ? counts[i] : 0;
    int s = c;
#pragma unroll
    for (int off = 1; off < 64; off <<= 1) {
        const int t = __shfl_up(s, off, 64);
        if (lane >= off) s += t;
    }
    __shared__ int wsum[4], wexcl[4];
    if (lane == 63) wsum[w] = s;
    __syncthreads();
    if (tid == 0) {
        int r = 0;
#pragma unroll
        for (int k = 0; k < 4; ++k) { wexcl[k] = r; r += wsum[k]; }
    }
    __syncthreads();
    if (i < NN) cursor[i] = bexcl[blockIdx.x] + wexcl[w] + s - c;
}

// ============================================================ scatter + edge-order cast
// Block handles 128 edges. tid<128: descriptor scatter sdat[pos] =
// {src|dst<<16, e} (random 8B writes, only 6.4MB). All 256 threads:
// cast ea rows to bf16 in EDGE ORDER — fully sequential reads AND writes
// (the sorted-ebs copy's random 64B writes were the 69us cost; moving the
// randomness to aggE's READ side avoids RFO/partial-line penalties and
// the 51MB eb table stays L3-resident for the gather).
__global__ __launch_bounds__(256)
void k_scatter2(const int* __restrict__ ei, int* __restrict__ cursor,
                const float* __restrict__ ea, int2* __restrict__ sdat,
                unsigned int* __restrict__ eb)
{
    const int tid = threadIdx.x;
    const int e0  = blockIdx.x * 128;
    if (tid < 128) {
        const int is64 = sniff64(ei);
        const int2* ei2 = (const int2*)ei;
        const int e   = e0 + tid;
        const int src = is64 ? ei2[e].x : ei[e];
        const int dst = is64 ? ei2[NE + e].x : ei[NE + e];
        const int pos = atomicAdd(&cursor[dst], 1);
        sdat[pos] = make_int2(src | (dst << 16), e);
    }
#pragma unroll
    for (int it = 0; it < 8; ++it) {
        const int idx = it * 256 + tid;          // 0..2047 uints in this block
        const float2 v = *reinterpret_cast<const float2*>(
                             ea + (size_t)e0 * ED + idx * 2);
        const unsigned lo = (unsigned short)f2bf(v.x);
        const unsigned hi = (unsigned short)f2bf(v.y);
        eb[(size_t)e0 * 16 + idx] = lo | (hi << 16);
    }
}

// ============================================================ aggregation
// One wave per TWO consecutive 32-edge dst-sorted chunks (atomic L2
// locality). B-fragments pre-converted from Bft (8x16B loads). A = bf16
// edge rows GATHERED from the L3-resident edge-order eb table (2x16B per
// lane). C-init = one uint2 (4 bf16 dims bb*32+col) per reg from the
// permuted xb gather; chunk1's gathers issued before chunk0's epilogue.
__device__ __forceinline__ void agg_epilogue(f32x16 (&C)[4], const float beb[4],
                                             int dstv, int lane, int col, int h,
                                             float* __restrict__ agg)
{
#pragma unroll
    for (int bb = 0; bb < 4; ++bb)
#pragma unroll
        for (int reg = 0; reg < 16; ++reg)
            C[bb][reg] = fmaxf(C[bb][reg] + beb[bb], 0.0f);

    const int  prv  = __shfl(dstv, (lane == 0) ? 0 : lane - 1, 64);
    const bool flag = (lane < 32) && ((col == 0) || (dstv != prv));
    unsigned rem = (unsigned)(__ballot(flag) & 0xFFFFFFFFull);

    while (rem) {
        const int ms = __ffs((int)rem) - 1;
        rem &= rem - 1;
        const int hi = rem ? (__ffs((int)rem) - 1) : 32;
        const int d  = __shfl(dstv, ms, 64);

        float v0 = 0.f, v1 = 0.f, v2 = 0.f, v3 = 0.f;
#pragma unroll
        for (int reg = 0; reg < 16; ++reg) {
            const int E = (reg & 3) + 8 * (reg >> 2) + 4 * h;
            const float mk = (E >= ms && E < hi) ? 1.0f : 0.0f;
            v0 = fmaf(mk, C[0][reg], v0);
            v1 = fmaf(mk, C[1][reg], v1);
            v2 = fmaf(mk, C[2][reg], v2);
            v3 = fmaf(mk, C[3][reg], v3);
        }
        v0 += __shfl_xor(v0, 32, 64);
        v1 += __shfl_xor(v1, 32, 64);
        v2 += __shfl_xor(v2, 32, 64);
        v3 += __shfl_xor(v3, 32, 64);

        float* ar = agg + (size_t)d * DD + h * 64 + col;
        unsafeAtomicAdd(ar,      h ? v2 : v0);
        unsafeAtomicAdd(ar + 32, h ? v3 : v1);
    }
}

__global__ __launch_bounds__(256, 2)
void k_aggE(const unsigned int* __restrict__ xb, const unsigned int* __restrict__ eb,
            const unsigned short* __restrict__ Bft, const float* __restrict__ be,
            const int2* __restrict__ sdat, float* __restrict__ agg)
{
    const int lane = threadIdx.x & 63;
    const int col  = lane & 31;
    const int h    = lane >> 5;
    const int wid  = (blockIdx.x << 2) | (threadIdx.x >> 6);   // 0..12499
    const int c0   = wid * 2, c1 = wid * 2 + 1;

    // B fragments: pre-converted, 8 x 16B per lane (L2-resident 8KB table)
    bf16x8 Bf[4][2];
    {
        const bf16x8* bp_ = reinterpret_cast<const bf16x8*>(Bft + lane * 64);
#pragma unroll
        for (int bb = 0; bb < 4; ++bb) {
            Bf[bb][0] = bp_[bb * 2];
            Bf[bb][1] = bp_[bb * 2 + 1];
        }
    }
    float beb[4];
#pragma unroll
    for (int bb = 0; bb < 4; ++bb) beb[bb] = be[bb * 32 + col];

    // descriptors for both chunks
    const int2 dv0 = sdat[(size_t)c0 * 32 + col];
    const int2 dv1 = sdat[(size_t)c1 * 32 + col];

    // A fragments: lane's edge rows gathered from edge-order eb (L3-resident)
    const unsigned int* ebr0 = eb + (size_t)dv0.y * 16;
    const unsigned int* ebr1 = eb + (size_t)dv1.y * 16;
    const bf16x8 A00 = *reinterpret_cast<const bf16x8*>(ebr0 + h * 4);
    const bf16x8 A01 = *reinterpret_cast<const bf16x8*>(ebr0 + 8 + h * 4);
    const bf16x8 A10 = *reinterpret_cast<const bf16x8*>(ebr1 + h * 4);
    const bf16x8 A11 = *reinterpret_cast<const bf16x8*>(ebr1 + 8 + h * 4);

    // chunk0 gathers
    uint2 w0[16];
#pragma unroll
    for (int reg = 0; reg < 16; ++reg) {
        const int E   = (reg & 3) + 8 * (reg >> 2) + 4 * h;
        const int src = __shfl(dv0.x, E, 64) & 0xFFFF;
        w0[reg] = *reinterpret_cast<const uint2*>(xb + (size_t)src * 64 + col * 2);
    }

    f32x16 C[4];
#pragma unroll
    for (int reg = 0; reg < 16; ++reg) {
        C[0][reg] = __uint_as_float(w0[reg].x << 16);
        C[1][reg] = __uint_as_float(w0[reg].x & 0xFFFF0000u);
        C[2][reg] = __uint_as_float(w0[reg].y << 16);
        C[3][reg] = __uint_as_float(w0[reg].y & 0xFFFF0000u);
    }
#pragma unroll
    for (int bb = 0; bb < 4; ++bb) {
        C[bb] = __builtin_amdgcn_mfma_f32_32x32x16_bf16(A00, Bf[bb][0], C[bb], 0, 0, 0);
        C[bb] = __builtin_amdgcn_mfma_f32_32x32x16_bf16(A01, Bf[bb][1], C[bb], 0, 0, 0);
    }

    // issue chunk1 gathers BEFORE chunk0 epilogue (latency hides under VALU)
    uint2 w1[16];
#pragma unroll
    for (int reg = 0; reg < 16; ++reg) {
        const int E   = (reg & 3) + 8 * (reg >> 2) + 4 * h;
        const int src = __shfl(dv1.x, E, 64) & 0xFFFF;
        w1[reg] = *reinterpret_cast<const uint2*>(xb + (size_t)src * 64 + col * 2);
    }

    agg_epilogue(C, beb, ((unsigned)dv0.x) >> 16, lane, col, h, agg);

    // chunk1
#pragma unroll
    for (int reg = 0; reg < 16; ++reg) {
        C[0][reg] = __uint_as_float(w1[reg].x << 16);
        C[1][reg] = __uint_as_float(w1[reg].x & 0xFFFF0000u);
        C[2][reg] = __uint_as_float(w1[reg].y << 16);
        C[3][reg] = __uint_as_float(w1[reg].y & 0xFFFF0000u);
    }
#pragma unroll
    for (int bb = 0; bb < 4; ++bb) {
        C[bb] = __builtin_amdgcn_mfma_f32_32x32x16_bf16(A10, Bf[bb][0], C[bb], 0, 0, 0);
        C[bb] = __builtin_amdgcn_mfma_f32_32x32x16_bf16(A11, Bf[bb][1], C[bb], 0, 0, 0);
    }
    agg_epilogue(C, beb, ((unsigned)dv1.x) >> 16, lane, col, h, agg);
}

// ============================================================ fused conv+gate
// Phase 1: conv = (x+agg)@Wc+bc, plain bf16 (Wc in sBh). Then sBh is
// re-staged with Wg and each wave parks its conv tile (f32) in its quarter
// of sBl as the gate-GEMM A-operand. Phase 2: z = conv@Wg(+imp row)+bg;
// epilogue: sigmoid, blend, out write, prop = out@Wp+bp. agg aliases out.
__global__ __launch_bounds__(256)
void k_cg(const float* __restrict__ x, const float* agg,
          const float* __restrict__ Wc, const float* __restrict__ bc,
          const float* __restrict__ imp, const float* __restrict__ Wg,
          const float* __restrict__ bg, const float* __restrict__ Wp,
          const float* __restrict__ bp, float* outp, float* __restrict__ prop)
{
    __shared__ short sBh[2048 * 8];   // 32KB: Wc, then Wg
    __shared__ short sBl[2048 * 8];   // 32KB: conv-tile scratch (phase 2)
    for (int idx = threadIdx.x; idx < 2048; idx += 256) {
        const int kk = idx >> 9;
        const int b  = (idx >> 6) & 7;
        const int l  = idx & 63;
        const int row0 = kk * 32 + ((l >> 4) << 3);
        const int col  = b * 16 + (l & 15);
        bf16x8 h8;
#pragma unroll
        for (int j = 0; j < 8; ++j)
            h8[j] = f2bf(Wc[(row0 + j) * DD + col]);
        *reinterpret_cast<bf16x8*>(&sBh[idx * 8]) = h8;
    }
    __syncthreads();

    const int lane = threadIdx.x & 63;
    const int ncol = lane & 15;
    const int krow = (lane >> 4) << 3;
    const int grp  = lane >> 4;
    const int wib  = threadIdx.x >> 6;
    const int wid  = (blockIdx.x << 2) | wib;
    const bool live = (wid < NN / 16);
    const int m0 = live ? wid * 16 : 0;

    // ---- phase 1: conv GEMM (plain bf16)
    f32x4 C[8];
#pragma unroll
    for (int b = 0; b < 8; ++b) {
        const float bcv = bc[b * 16 + ncol];
        f32x4 c = { bcv, bcv, bcv, bcv };
        C[b] = c;
    }
    {
        const float* xrow = x   + (size_t)(m0 + ncol) * DD + krow;
        const float* grow = agg + (size_t)(m0 + ncol) * DD + krow;
#pragma unroll
        for (int kk = 0; kk < 4; ++kk) {
            const float4 x0 = ld4(xrow + kk * 32), x1 = ld4(xrow + kk * 32 + 4);
            const float4 g0 = ld4(grow + kk * 32), g1 = ld4(grow + kk * 32 + 4);
            const float av[8] = { x0.x + g0.x, x0.y + g0.y, x0.z + g0.z, x0.w + g0.w,
                                  x1.x + g1.x, x1.y + g1.y, x1.z + g1.z, x1.w + g1.w };
            bf16x8 Ah;
#pragma unroll
            for (int j = 0; j < 8; ++j) Ah[j] = f2bf(av[j]);
#pragma unroll
            for (int b = 0; b < 8; ++b) {
                const bf16x8 Bh = *reinterpret_cast<const bf16x8*>(&sBh[((kk * 8 + b) * 64 + lane) * 8]);
                C[b] = __builtin_amdgcn_mfma_f32_16x16x32_bf16(Ah, Bh, C[b], 0, 0, 0);
            }
        }
    }
    __syncthreads();   // everyone done reading Wc

    // ---- restage: Wg -> sBh (cooperative); conv tile -> sBl (per wave)
    for (int idx = threadIdx.x; idx < 2048; idx += 256) {
        const int kk = idx >> 9;
        const int b  = (idx >> 6) & 7;
        const int l  = idx & 63;
        const int row0 = kk * 32 + ((l >> 4) << 3);
        const int col  = b * 16 + (l & 15);
        bf16x8 h8;
#pragma unroll
        for (int j = 0; j < 8; ++j)
            h8[j] = f2bf(Wg[(row0 + j) * DD + col]);
        *reinterpret_cast<bf16x8*>(&sBh[idx * 8]) = h8;
    }
    float* scr = reinterpret_cast<float*>(sBl) + wib * 2048;   // 16x128 f32
#pragma unroll
    for (int r = 0; r < 4; ++r)
#pragma unroll
        for (int b = 0; b < 8; ++b)
            scr[(grp * 4 + r) * DD + b * 16 + ncol] = C[b][r];
    __syncthreads();

    // ---- phase 2: z GEMM (plain bf16)
    f32x4 Z[8];
#pragma unroll
    for (int b = 0; b < 8; ++b) {
        const float bgv = bg[b * 16 + ncol];
        f32x4 z = { bgv, bgv, bgv, bgv };
        Z[b] = z;
    }
#pragma unroll
    for (int kk = 0; kk < 4; ++kk) {
        const float4 a0 = ld4(scr + ncol * DD + kk * 32 + krow);
        const float4 a1 = ld4(scr + ncol * DD + kk * 32 + krow + 4);
        const float av[8] = { a0.x, a0.y, a0.z, a0.w, a1.x, a1.y, a1.z, a1.w };
        bf16x8 Ah;
#pragma unroll
        for (int j = 0; j < 8; ++j) Ah[j] = f2bf(av[j]);
#pragma unroll
        for (int b = 0; b < 8; ++b) {
            const bf16x8 Bh = *reinterpret_cast<const bf16x8*>(&sBh[((kk * 8 + b) * 64 + lane) * 8]);
            Z[b] = __builtin_amdgcn_mfma_f32_16x16x32_bf16(Ah, Bh, Z[b], 0, 0, 0);
        }
    }

    if (!live) return;

    // ---- epilogue
    float wgi[8], wp8[8];
#pragma unroll
    for (int b = 0; b < 8; ++b) {
        wgi[b] = Wg[DD * DD + b * 16 + ncol];   // importance row (row 128)
        wp8[b] = Wp[b * 16 + ncol];
    }
    const float bps = bp[0];

    float s[4] = { 0.f, 0.f, 0.f, 0.f };
#pragma unroll
    for (int r = 0; r < 4; ++r) {
        const int m = m0 + grp * 4 + r;
        const float im = imp[m];
        const float* xr = x + (size_t)m * DD + ncol;
        float* orow = outp + (size_t)m * DD + ncol;
#pragma unroll
        for (int b = 0; b < 8; ++b) {
            const float a = Z[b][r] + im * wgi[b];
            const float g = 1.0f / (1.0f + expf(-a));
            const float xv = xr[b * 16];
            const float o = fmaf(g, C[b][r] - xv, xv);
            orow[b * 16] = o;
            s[r] += o * wp8[b];
        }
    }
#pragma unroll
    for (int off = 1; off < 16; off <<= 1) {
        s[0] += __shfl_xor(s[0], off, 64);
        s[1] += __shfl_xor(s[1], off, 64);
        s[2] += __shfl_xor(s[2], off, 64);
        s[3] += __shfl_xor(s[3], off, 64);
    }
    if (ncol < 4) {
        const float v = (ncol == 0) ? s[0] : (ncol == 1) ? s[1] : (ncol == 2) ? s[2] : s[3];
        prop[m0 + grp * 4 + ncol] = v + bps;
    }
}

extern "C" void kernel_launch(void* const* d_in, const int* in_sizes, int n_in,
                              void* d_out, int out_size, void* d_ws, size_t ws_size,
                              hipStream_t stream) {
    const float* x   = (const float*)d_in[0];
    const int*   ei  = (const int*)d_in[1];
    const float* ea  = (const float*)d_in[2];
    const float* imp = (const float*)d_in[3];
    const float* We  = (const float*)d_in[4];
    const float* be  = (const float*)d_in[5];
    const float* Wc  = (const float*)d_in[6];
    const float* bc  = (const float*)d_in[7];
    const float* Wg  = (const float*)d_in[8];
    const float* bg  = (const float*)d_in[9];
    const float* Wp  = (const float*)d_in[10];
    const float* bp  = (const float*)d_in[11];

    float* out  = (float*)d_out;                 // [NN, DD]; doubles as agg
    float* prop = out + (size_t)NN * DD;         // [NN]
    float* agg  = out;                           // aliased (see k_cg note)

    // ws layout (~71.4 MB; 74.6 MB proven available in R8)
    int*            counts = (int*)d_ws;                               // NN
    int*            cursor = (int*)((char*)d_ws + 204800);             // NN
    int*            bsum   = (int*)((char*)d_ws + 409600);             // NB
    int*            bexcl  = (int*)((char*)d_ws + 413696);             // NB
    unsigned short* Bft    = (unsigned short*)((char*)d_ws + 417792);  // 64*64 u16
    int2*           sdat   = (int2*)((char*)d_ws + 1048576);           // NE int2
    unsigned int*   xb     = (unsigned int*)((char*)d_ws + 7448576);   // NN*DD bf16 (permuted)
    unsigned int*   eb     = (unsigned int*)((char*)d_ws + 20248576);  // NE*ED bf16 (edge order)

    hipMemsetAsync(counts, 0, NN * sizeof(int), stream);
    hipMemsetAsync(agg, 0, (size_t)NN * DD * sizeof(float), stream);
    hipLaunchKernelGGL(k_setup,    dim3(8299), dim3(256), 0, stream,
                       x, ei, We, xb, counts, Bft);
    hipLaunchKernelGGL(k_bsum,     dim3(NB),   dim3(256), 0, stream, counts, bsum);
    hipLaunchKernelGGL(k_scanb,    dim3(1),    dim3(256), 0, stream, bsum, bexcl);
    hipLaunchKernelGGL(k_rowptr,   dim3(NB),   dim3(256), 0, stream, counts, bexcl, cursor);
    hipLaunchKernelGGL(k_scatter2, dim3(6250), dim3(256), 0, stream,
                       ei, cursor, ea, sdat, eb);
    hipLaunchKernelGGL(k_aggE,     dim3(3125), dim3(256), 0, stream,
                       xb, eb, Bft, be, sdat, agg);
    hipLaunchKernelGGL(k_cg,       dim3(782),  dim3(256), 0, stream,
                       x, agg, Wc, bc, imp, Wg, bg, Wp, bp, out, prop);
}